// Round 1
// baseline (335.462 us; speedup 1.0000x reference)
//
#include <hip/hip_runtime.h>

// Problem constants (from reference)
#define N_GRAPHS 4096
#define N_NODES  262144   // 4096 * 64
#define D        256      // EMBED_DIM
#define K2       512      // 2 * D
#define T        128      // TARGET_SIZE
#define GPB      16       // graphs per block

// ---------------------------------------------------------------------------
// Kernel A: offsets[bid] = first global node index of graph bid.
// batch_ids is sorted; detect boundaries. Writes every offset exactly once.
// ---------------------------------------------------------------------------
__global__ __launch_bounds__(256) void offsets_kernel(
    const int* __restrict__ batch_ids, int* __restrict__ offsets, int n_nodes)
{
    int i = blockIdx.x * blockDim.x + threadIdx.x;
    if (i >= n_nodes) return;
    int bid = batch_ids[i];
    if (i == 0 || batch_ids[i - 1] != bid) offsets[bid] = i;
}

// ---------------------------------------------------------------------------
// Kernel B: fused gather + GEMM.
// Block = 256 threads, handles GPB=16 graphs (grid = 256 blocks = 1/CU).
// Phase 1: gather 16 graphs x 512 f32 (two emb rows each) into LDS.
//          float4 loads from emb (coalesced), ds_write_b128 (conflict-free).
// Phase 2: thread t = (j = t&127, gg = t>>7). Each thread computes out[:, j]
//          for 8 graphs. Per 4-k step: 4 coalesced W loads + 8 broadcast
//          ds_read_b128 (all lanes same addr) + 32 FMAs.
// ---------------------------------------------------------------------------
__global__ __launch_bounds__(256) void decoder_kernel(
    const float* __restrict__ emb,
    const int*   __restrict__ targets,
    const int*   __restrict__ offsets,
    const float* __restrict__ W,
    const float* __restrict__ bias,
    float*       __restrict__ out)
{
    __shared__ float xs[GPB][K2];     // 32 KB
    __shared__ int   rows[GPB][2];

    const int tid = threadIdx.x;
    const int g0  = blockIdx.x * GPB;

    // resolve the two endpoint rows of each of this block's graphs
    if (tid < GPB * 2) {
        int g = tid >> 1;
        int e = tid & 1;
        int t = targets[(g0 + g) * 2 + e];
        rows[g][e] = offsets[g0 + g] + t;
    }
    __syncthreads();

    // ---- Phase 1: gather. 16 graphs * 2 rows * 64 float4 = 2048 float4.
    const float4* emb4 = (const float4*)emb;
    #pragma unroll
    for (int it = 0; it < (GPB * 2 * 64) / 256; ++it) {
        int f      = tid + it * 256;
        int col4   = f & 63;          // float4 column within the row
        int rowsel = (f >> 6) & 1;    // endpoint 0 or 1
        int g      = f >> 7;          // graph within block
        int row    = rows[g][rowsel];
        float4 v   = emb4[row * (D / 4) + col4];
        *(float4*)&xs[g][rowsel * D + col4 * 4] = v;
    }
    __syncthreads();

    // ---- Phase 2: GEMM. out[g, j] = b[j] + sum_k xs[g][k] * W[k, j]
    const int j  = tid & (T - 1);
    const int gg = tid >> 7;          // which half of the 16 graphs

    float acc[8];
    const float bj = bias[j];
    #pragma unroll
    for (int p = 0; p < 8; ++p) acc[p] = bj;

    const float* Wj = W + j;          // column j, stride T

    #pragma unroll 2
    for (int k4 = 0; k4 < K2 / 4; ++k4) {
        const float w0 = Wj[(k4 * 4 + 0) * T];
        const float w1 = Wj[(k4 * 4 + 1) * T];
        const float w2 = Wj[(k4 * 4 + 2) * T];
        const float w3 = Wj[(k4 * 4 + 3) * T];
        #pragma unroll
        for (int p = 0; p < 8; ++p) {
            float4 xv = *(const float4*)&xs[gg * 8 + p][k4 * 4];
            acc[p] = fmaf(xv.x, w0, acc[p]);
            acc[p] = fmaf(xv.y, w1, acc[p]);
            acc[p] = fmaf(xv.z, w2, acc[p]);
            acc[p] = fmaf(xv.w, w3, acc[p]);
        }
    }

    #pragma unroll
    for (int p = 0; p < 8; ++p) {
        out[(g0 + gg * 8 + p) * T + j] = acc[p];
    }
}

// ---------------------------------------------------------------------------
extern "C" void kernel_launch(void* const* d_in, const int* in_sizes, int n_in,
                              void* d_out, int out_size, void* d_ws, size_t ws_size,
                              hipStream_t stream)
{
    const float* batch_emb = (const float*)d_in[0];
    const int*   batch_ids = (const int*)d_in[1];
    const int*   targets   = (const int*)d_in[2];
    const float* W         = (const float*)d_in[3];
    const float* bias      = (const float*)d_in[4];
    float*       out       = (float*)d_out;

    int* offsets = (int*)d_ws;   // N_GRAPHS ints

    offsets_kernel<<<N_NODES / 256, 256, 0, stream>>>(batch_ids, offsets, N_NODES);
    decoder_kernel<<<N_GRAPHS / GPB, 256, 0, stream>>>(
        batch_emb, targets, offsets, W, bias, out);
}

// Round 2
// 326.010 us; speedup vs baseline: 1.0290x; 1.0290x over previous
//
#include <hip/hip_runtime.h>

// Problem constants (from reference)
#define N_GRAPHS 4096
#define N_NODES  262144   // 4096 * 64
#define D        256      // EMBED_DIM
#define K2       512      // 2 * D
#define T        128      // TARGET_SIZE
#define GPB      8        // graphs per block (v2: 8 -> 512 blocks = 2/CU)

// ---------------------------------------------------------------------------
// Kernel A: offsets[bid] = first global node index of graph bid.
// batch_ids is sorted; detect boundaries. int4-vectorized: each thread
// inspects 4 consecutive ids (+1 scalar peek at the previous element).
// ---------------------------------------------------------------------------
__global__ __launch_bounds__(256) void offsets_kernel(
    const int* __restrict__ batch_ids, int* __restrict__ offsets)
{
    int i = blockIdx.x * blockDim.x + threadIdx.x;   // group of 4 ids
    const int4* v4 = (const int4*)batch_ids;
    int4 v = v4[i];
    int prev = (i == 0) ? -1 : batch_ids[i * 4 - 1];
    int base = i * 4;
    if (v.x != prev) offsets[v.x] = base;
    if (v.y != v.x)  offsets[v.y] = base + 1;
    if (v.z != v.y)  offsets[v.z] = base + 2;
    if (v.w != v.z)  offsets[v.w] = base + 3;
}

// ---------------------------------------------------------------------------
// Kernel B: fused gather + GEMM.
// Block = 256 threads, GPB=8 graphs, grid = 512 blocks (2 blocks/CU ->
// 2 waves/SIMD for latency hiding).
// Phase 1: gather 8 graphs x 512 f32 into LDS (float4, coalesced).
// Phase 2: thread t = (j = t&127, gg = t>>7). Each thread computes out[:, j]
//          for 4 graphs. Per 4-k step: 4 W loads (prefetched one step ahead)
//          + 4 broadcast ds_read_b128 + 16 FMAs on 4 independent acc chains.
// ---------------------------------------------------------------------------
__global__ __launch_bounds__(256) void decoder_kernel(
    const float* __restrict__ emb,
    const int*   __restrict__ targets,
    const int*   __restrict__ offsets,
    const float* __restrict__ W,
    const float* __restrict__ bias,
    float*       __restrict__ out)
{
    __shared__ float xs[GPB][K2];     // 16 KB
    __shared__ int   rows[GPB][2];

    const int tid = threadIdx.x;
    const int g0  = blockIdx.x * GPB;

    // resolve the two endpoint rows of each of this block's graphs
    if (tid < GPB * 2) {
        int g = tid >> 1;
        int e = tid & 1;
        int t = targets[(g0 + g) * 2 + e];
        rows[g][e] = offsets[g0 + g] + t;
    }
    __syncthreads();

    // ---- Phase 1: gather. 8 graphs * 2 rows * 64 float4 = 1024 float4.
    const float4* emb4 = (const float4*)emb;
    #pragma unroll
    for (int it = 0; it < (GPB * 2 * 64) / 256; ++it) {
        int f      = tid + it * 256;
        int col4   = f & 63;          // float4 column within the row
        int rowsel = (f >> 6) & 1;    // endpoint 0 or 1
        int g      = f >> 7;          // graph within block
        int row    = rows[g][rowsel];
        float4 v   = emb4[row * (D / 4) + col4];
        *(float4*)&xs[g][rowsel * D + col4 * 4] = v;
    }
    __syncthreads();

    // ---- Phase 2: GEMM. out[g, j] = b[j] + sum_k xs[g][k] * W[k, j]
    const int j  = tid & (T - 1);
    const int gg = tid >> 7;          // which half of the 8 graphs

    float acc0, acc1, acc2, acc3;
    {
        const float bj = bias[j];
        acc0 = bj; acc1 = bj; acc2 = bj; acc3 = bj;
    }

    const float* Wj = W + j;          // column j, stride T
    const float* xb0 = &xs[gg * 4 + 0][0];
    const float* xb1 = &xs[gg * 4 + 1][0];
    const float* xb2 = &xs[gg * 4 + 2][0];
    const float* xb3 = &xs[gg * 4 + 3][0];

    // prefetch k4 = 0
    float w0 = Wj[0 * T];
    float w1 = Wj[1 * T];
    float w2 = Wj[2 * T];
    float w3 = Wj[3 * T];

    #pragma unroll 4
    for (int k4 = 0; k4 < K2 / 4; ++k4) {
        // prefetch next step's W scalars (dead past the end; guarded)
        float nw0 = 0.f, nw1 = 0.f, nw2 = 0.f, nw3 = 0.f;
        if (k4 + 1 < K2 / 4) {
            const float* Wn = Wj + (k4 + 1) * 4 * T;
            nw0 = Wn[0 * T];
            nw1 = Wn[1 * T];
            nw2 = Wn[2 * T];
            nw3 = Wn[3 * T];
        }

        const int kb = k4 * 4;
        float4 x0 = *(const float4*)(xb0 + kb);
        float4 x1 = *(const float4*)(xb1 + kb);
        float4 x2 = *(const float4*)(xb2 + kb);
        float4 x3 = *(const float4*)(xb3 + kb);

        acc0 = fmaf(x0.x, w0, acc0); acc0 = fmaf(x0.y, w1, acc0);
        acc0 = fmaf(x0.z, w2, acc0); acc0 = fmaf(x0.w, w3, acc0);
        acc1 = fmaf(x1.x, w0, acc1); acc1 = fmaf(x1.y, w1, acc1);
        acc1 = fmaf(x1.z, w2, acc1); acc1 = fmaf(x1.w, w3, acc1);
        acc2 = fmaf(x2.x, w0, acc2); acc2 = fmaf(x2.y, w1, acc2);
        acc2 = fmaf(x2.z, w2, acc2); acc2 = fmaf(x2.w, w3, acc2);
        acc3 = fmaf(x3.x, w0, acc3); acc3 = fmaf(x3.y, w1, acc3);
        acc3 = fmaf(x3.z, w2, acc3); acc3 = fmaf(x3.w, w3, acc3);

        w0 = nw0; w1 = nw1; w2 = nw2; w3 = nw3;
    }

    out[(g0 + gg * 4 + 0) * T + j] = acc0;
    out[(g0 + gg * 4 + 1) * T + j] = acc1;
    out[(g0 + gg * 4 + 2) * T + j] = acc2;
    out[(g0 + gg * 4 + 3) * T + j] = acc3;
}

// ---------------------------------------------------------------------------
extern "C" void kernel_launch(void* const* d_in, const int* in_sizes, int n_in,
                              void* d_out, int out_size, void* d_ws, size_t ws_size,
                              hipStream_t stream)
{
    const float* batch_emb = (const float*)d_in[0];
    const int*   batch_ids = (const int*)d_in[1];
    const int*   targets   = (const int*)d_in[2];
    const float* W         = (const float*)d_in[3];
    const float* bias      = (const float*)d_in[4];
    float*       out       = (float*)d_out;

    int* offsets = (int*)d_ws;   // N_GRAPHS ints

    offsets_kernel<<<N_NODES / 4 / 256, 256, 0, stream>>>(batch_ids, offsets);
    decoder_kernel<<<N_GRAPHS / GPB, 256, 0, stream>>>(
        batch_emb, targets, offsets, W, bias, out);
}